// Round 4
// baseline (2905.876 us; speedup 1.0000x reference)
//
#include <hip/hip_runtime.h>
#include <hip/hip_bf16.h>
#include <math.h>

typedef unsigned short u16;
typedef __attribute__((ext_vector_type(8))) short short8;
typedef __attribute__((ext_vector_type(4))) float f32x4;

__device__ __forceinline__ u16 f2bf(float f) {
  union { float f; unsigned u; } v; v.f = f;
  unsigned r = v.u + 0x7fffu + ((v.u >> 16) & 1u);
  return (u16)(r >> 16);
}

// async global->LDS, 16B/lane. LDS dest is wave-uniform base; HW adds lane*16.
__device__ __forceinline__ void glds16(const u16* g, u16* l) {
  __builtin_amdgcn_global_load_lds(
      (const __attribute__((address_space(1))) void*)g,
      (__attribute__((address_space(3))) void*)l, 16, 0, 0);
}

// ===========================================================================
// Diffusion: out[(b*512+node)*ldz + (1+tc)*C + coff0 + ch] =
//            sum_k Tpow[tc][node][k] * zT[ch][b*512+k]
// zT layout: [ch][16384]. grid.z = b*6 + tc. Dual-write ch<Fdual into zdual.
// ===========================================================================
template<int BM, int BN, int WR, int WC>
__global__ __launch_bounds__(256) void gemm_diff(
    const u16* __restrict__ Tpow, const u16* __restrict__ zT,
    u16* __restrict__ zout, int ldz, int C, int coff0,
    u16* __restrict__ zdual, int Fdual)
{
  constexpr int BK = 32;
  constexpr int FM = BM / (WR * 16), FN = BN / (WC * 16);
  __shared__ u16 sm[(BM + BN) * BK];
  const int tid = threadIdx.x, lane = tid & 63, wid = tid >> 6;
  const int wr = wid / WC, wc = wid % WC;
  const int l15 = lane & 15, l4 = lane >> 4;
  const int m0 = blockIdx.x * BM;
  const int y0 = blockIdx.y * BN;
  const int b = blockIdx.z / 6, tc = blockIdx.z % 6;
  const u16* A = Tpow + (long)tc * 512 * 512;
  const u16* Bz = zT + (long)y0 * 16384 + b * 512;

  f32x4 acc[FM][FN] = {};
  for (int k0 = 0; k0 < 512; k0 += BK) {
    for (int s = tid; s < (BM + BN) * 4; s += 256) {
      const u16* gp;
      if (s < BM * 4) { int m = s >> 2, kc = s & 3; gp = A + (long)(m0 + m) * 512 + k0 + kc * 8; }
      else { int q = s - BM * 4; int n = q >> 2, kc = q & 3; gp = Bz + (long)n * 16384 + k0 + kc * 8; }
      glds16(gp, sm + (s - lane) * 8);
    }
    __syncthreads();
    short8 af[FM], bf[FN];
    #pragma unroll
    for (int i = 0; i < FM; i++)
      af[i] = *(const short8*)&sm[(wr * FM * 16 + i * 16 + l15) * BK + l4 * 8];
    #pragma unroll
    for (int j = 0; j < FN; j++)
      bf[j] = *(const short8*)&sm[BM * BK + (wc * FN * 16 + j * 16 + l15) * BK + l4 * 8];
    #pragma unroll
    for (int i = 0; i < FM; i++)
      #pragma unroll
      for (int j = 0; j < FN; j++)
        acc[i][j] = __builtin_amdgcn_mfma_f32_16x16x32_bf16(af[i], bf[j], acc[i][j], 0, 0, 0);
    __syncthreads();
  }

  const int tC = (1 + tc) * C;
  #pragma unroll
  for (int i = 0; i < FM; i++) {
    #pragma unroll
    for (int j = 0; j < FN; j++) {
      int node = m0 + wr * FM * 16 + i * 16 + l4 * 4;
      int ch = y0 + wc * FN * 16 + j * 16 + l15;
      #pragma unroll
      for (int rr = 0; rr < 4; rr++) {
        u16 v = f2bf(acc[i][j][rr]);
        long r = (long)b * 512 + node + rr;
        zout[r * ldz + tC + coff0 + ch] = v;
        if (Fdual && ch < Fdual) zdual[r * ldz + tC + ch] = v;
      }
    }
  }
}

// ===========================================================================
// Projection (giant-M): out(16384, Nout) = act(z(16384, K) @ W(Nout, K)^T + bias)
// MODE 1 (gates): n<128 -> rh = sig*hst -> zc[r*ldzc+Foff+n] (bf16) + zTc[n*16384+r];
//                 n>=128 -> ubuf[r*128+n-128] (fp32).
// MODE 2 (cand):  tanh -> outbuf[r*128+n] (fp32).
// ===========================================================================
template<int BM, int BN, int MODE>
__global__ __launch_bounds__(256) void gemm_proj(
    const u16* __restrict__ Az, int ldA,
    const u16* __restrict__ W, int K,
    const float* __restrict__ bias,
    const float* __restrict__ hst,
    u16* __restrict__ zc, int ldzc, int Foff,
    u16* __restrict__ zTc,
    float* __restrict__ outbuf)
{
  constexpr int BK = 32;
  constexpr int FM = BM / 32, FN = BN / 32;   // WR = WC = 2
  __shared__ u16 sm[(BM + BN) * BK];
  const int tid = threadIdx.x, lane = tid & 63, wid = tid >> 6;
  const int wr = wid >> 1, wc = wid & 1;
  const int l15 = lane & 15, l4 = lane >> 4;
  const int m0 = blockIdx.x * BM;
  const int n0 = blockIdx.y * BN;

  f32x4 acc[FM][FN] = {};
  for (int k0 = 0; k0 < K; k0 += BK) {
    for (int s = tid; s < (BM + BN) * 4; s += 256) {
      const u16* gp;
      if (s < BM * 4) { int m = s >> 2, kc = s & 3; gp = Az + (long)(m0 + m) * ldA + k0 + kc * 8; }
      else { int q = s - BM * 4; int n = q >> 2, kc = q & 3; gp = W + (long)(n0 + n) * K + k0 + kc * 8; }
      glds16(gp, sm + (s - lane) * 8);
    }
    __syncthreads();
    short8 af[FM], bf[FN];
    #pragma unroll
    for (int i = 0; i < FM; i++)
      af[i] = *(const short8*)&sm[(wr * FM * 16 + i * 16 + l15) * BK + l4 * 8];
    #pragma unroll
    for (int j = 0; j < FN; j++)
      bf[j] = *(const short8*)&sm[BM * BK + (wc * FN * 16 + j * 16 + l15) * BK + l4 * 8];
    #pragma unroll
    for (int i = 0; i < FM; i++)
      #pragma unroll
      for (int j = 0; j < FN; j++)
        acc[i][j] = __builtin_amdgcn_mfma_f32_16x16x32_bf16(af[i], bf[j], acc[i][j], 0, 0, 0);
    __syncthreads();
  }

  #pragma unroll
  for (int i = 0; i < FM; i++) {
    #pragma unroll
    for (int j = 0; j < FN; j++) {
      int mb = m0 + wr * FM * 16 + i * 16 + l4 * 4;
      int n = n0 + wc * FN * 16 + j * 16 + l15;
      #pragma unroll
      for (int rr = 0; rr < 4; rr++) {
        float v = acc[i][j][rr] + bias[n];
        long r = mb + rr;
        if constexpr (MODE == 1) {
          float g = 1.f / (1.f + expf(-v));
          if (n < 128) {
            float rh = g * hst[r * 128 + n];
            u16 hv = f2bf(rh);
            zc[r * ldzc + Foff + n] = hv;
            zTc[(long)n * 16384 + r] = hv;
          } else {
            outbuf[r * 128 + (n - 128)] = g;
          }
        } else {
          outbuf[r * 128 + n] = tanhf(v);
        }
      }
    }
  }
}

// ===========================================================================
// Fused GRU update + LayerNorm (H=128) + fan-out writes.
// Block: 64 nodes x 128 ch; grid (8, B).
// ===========================================================================
__global__ __launch_bounds__(256) void gru_ln(
    const float* __restrict__ ub, const float* __restrict__ cd,
    float* __restrict__ h, const float* __restrict__ gamma, const float* __restrict__ beta,
    u16* __restrict__ rm0, int ld0, int co0,
    u16* __restrict__ rm1, int ld1, int co1,
    u16* __restrict__ rm2, int ld2, int co2,
    u16* __restrict__ cm0, int ro0,
    u16* __restrict__ cm1, int ro1)
{
  __shared__ float hs[64][132];
  const int tid = threadIdx.x;
  const long b = blockIdx.y;
  const int n0 = blockIdx.x * 64;
  const long rbase = (b * 512 + n0) * 128;

  #pragma unroll
  for (int i = 0; i < 32; i++) {
    int idx = tid + i * 256;
    float u = ub[rbase + idx];
    float cc = cd[rbase + idx];
    float hv = h[rbase + idx];
    hs[idx >> 7][idx & 127] = (1.f - u) * hv + u * cc;
  }
  __syncthreads();

  const int rw = tid >> 2, sub = tid & 3;
  float s = 0.f, s2v = 0.f;
  #pragma unroll
  for (int i = 0; i < 32; i++) {
    float v = hs[rw][sub + 4 * i];
    s += v; s2v += v * v;
  }
  s += __shfl_xor(s, 1); s2v += __shfl_xor(s2v, 1);
  s += __shfl_xor(s, 2); s2v += __shfl_xor(s2v, 2);
  float mu = s * (1.f / 128.f);
  float var = s2v * (1.f / 128.f) - mu * mu;
  float rs = rsqrtf(var + 1e-5f);
  #pragma unroll
  for (int i = 0; i < 32; i++) {
    int c = sub + 4 * i;
    float v = (hs[rw][c] - mu) * rs * gamma[c] + beta[c];
    h[rbase + rw * 128 + c] = v;
    hs[rw][c] = v;
  }
  __syncthreads();

  #pragma unroll
  for (int i = 0; i < 32; i++) {
    int idx = tid + i * 256;
    int node = idx >> 7, c = idx & 127;
    u16 v = f2bf(hs[node][c]);
    long r = b * 512 + n0 + node;
    rm0[r * ld0 + co0 + c] = v;
    if (rm1) rm1[r * ld1 + co1 + c] = v;
    if (rm2) rm2[r * ld2 + co2 + c] = v;
  }
  const int c2 = tid >> 1, half = tid & 1;
  u16 tmp[32];
  #pragma unroll
  for (int i = 0; i < 32; i++) tmp[i] = f2bf(hs[half * 32 + i][c2]);
  const short8* tv = (const short8*)tmp;
  {
    long off = (long)(ro0 + c2) * 16384 + b * 512 + n0 + half * 32;
    #pragma unroll
    for (int q = 0; q < 4; q++) *(short8*)&cm0[off + q * 8] = tv[q];
  }
  if (cm1) {
    long off = (long)(ro1 + c2) * 16384 + b * 512 + n0 + half * 32;
    #pragma unroll
    for (int q = 0; q < 4; q++) *(short8*)&cm1[off + q * 8] = tv[q];
  }
}

// ===========================================================================
// small helpers
// ===========================================================================
__global__ __launch_bounds__(256) void xk(
    const float* __restrict__ xs, int t,
    u16* __restrict__ z0g, u16* __restrict__ z0c, u16* __restrict__ z0Tg)
{
  int r = blockIdx.x * 256 + threadIdx.x;       // 0..16383 = b*512+n
  int b = r >> 9, n = r & 511;
  const float* src = xs + (((long)b * 8 + t) * 512 + n) * 16;
  u16 tmp[16];
  #pragma unroll
  for (int f = 0; f < 16; f++) tmp[f] = f2bf(src[f]);
  const short8* tv = (const short8*)tmp;
  *(short8*)&z0g[(long)r * 1024] = tv[0];
  *(short8*)&z0g[(long)r * 1024 + 8] = tv[1];
  *(short8*)&z0c[(long)r * 1024] = tv[0];
  *(short8*)&z0c[(long)r * 1024 + 8] = tv[1];
  #pragma unroll
  for (int f = 0; f < 16; f++) z0Tg[(long)f * 16384 + r] = tmp[f];
}

__global__ void zero_cols(u16* __restrict__ z, int ld, int c0) {  // zero 128 cols
  int idx = blockIdx.x * 256 + threadIdx.x;     // 16384*16
  int r = idx >> 4, s = idx & 15;
  short8 zz = {};
  *(short8*)&z[(long)r * ld + c0 + s * 8] = zz;
}

__global__ void cvtT(const float* __restrict__ Tf, const float* __restrict__ Tb,
                     u16* __restrict__ Tpow, u16* __restrict__ TfT, u16* __restrict__ TbT)
{
  int idx = blockIdx.x * 256 + threadIdx.x;     // 262144
  int i = idx >> 9, j = idx & 511;
  const float* s = blockIdx.y ? Tb : Tf;
  u16* d = Tpow + (blockIdx.y ? 3 : 0) * 262144;
  u16* dT = blockIdx.y ? TbT : TfT;
  u16 v = f2bf(s[idx]);
  d[idx] = v;
  dT[(long)j * 512 + i] = v;
}

__global__ __launch_bounds__(256) void gemm_pow(
    const u16* __restrict__ A0, const u16* __restrict__ B0, u16* __restrict__ C0,
    const u16* __restrict__ A1, const u16* __restrict__ B1, u16* __restrict__ C1)
{
  constexpr int BM = 64, BN = 64, BK = 32;
  __shared__ u16 sm[(BM + BN) * BK];
  const int tid = threadIdx.x, lane = tid & 63, wid = tid >> 6;
  const int wr = wid >> 1, wc = wid & 1;
  const int l15 = lane & 15, l4 = lane >> 4;
  const int m0 = blockIdx.x * BM, n0 = blockIdx.y * BN;
  const u16* A = blockIdx.z ? A1 : A0;
  const u16* Bt = blockIdx.z ? B1 : B0;
  u16* Cc = blockIdx.z ? C1 : C0;

  f32x4 acc[2][2] = {};
  for (int k0 = 0; k0 < 512; k0 += BK) {
    for (int s = tid; s < (BM + BN) * 4; s += 256) {
      const u16* gp;
      if (s < BM * 4) { int m = s >> 2, kc = s & 3; gp = A + (long)(m0 + m) * 512 + k0 + kc * 8; }
      else { int q = s - BM * 4; int n = q >> 2, kc = q & 3; gp = Bt + (long)(n0 + n) * 512 + k0 + kc * 8; }
      glds16(gp, sm + (s - lane) * 8);
    }
    __syncthreads();
    short8 af[2], bf[2];
    #pragma unroll
    for (int i = 0; i < 2; i++)
      af[i] = *(const short8*)&sm[(wr * 32 + i * 16 + l15) * BK + l4 * 8];
    #pragma unroll
    for (int j = 0; j < 2; j++)
      bf[j] = *(const short8*)&sm[BM * BK + (wc * 32 + j * 16 + l15) * BK + l4 * 8];
    #pragma unroll
    for (int i = 0; i < 2; i++)
      #pragma unroll
      for (int j = 0; j < 2; j++)
        acc[i][j] = __builtin_amdgcn_mfma_f32_16x16x32_bf16(af[i], bf[j], acc[i][j], 0, 0, 0);
    __syncthreads();
  }
  #pragma unroll
  for (int i = 0; i < 2; i++)
    #pragma unroll
    for (int j = 0; j < 2; j++) {
      int mb = m0 + wr * 32 + i * 16 + l4 * 4;
      int n = n0 + wc * 32 + j * 16 + l15;
      #pragma unroll
      for (int rr = 0; rr < 4; rr++)
        Cc[(long)(mb + rr) * 512 + n] = f2bf(acc[i][j][rr]);
    }
}

__global__ void wt_cvt(const float* __restrict__ W, u16* __restrict__ Wt,
                       int Ksrc, int Kpad, int Nout) {
  long idx = (long)blockIdx.x * 256 + threadIdx.x;
  if (idx >= (long)Nout * Kpad) return;
  int o = (int)(idx / Kpad), k = (int)(idx % Kpad);
  Wt[idx] = f2bf(k < Ksrc ? W[(long)k * Nout + o] : 0.f);
}

// ===========================================================================
extern "C" void kernel_launch(void* const* d_in, const int* in_sizes, int n_in,
                              void* d_out, int out_size, void* d_ws, size_t ws_size,
                              hipStream_t stream) {
  const float* x_seq = (const float*)d_in[0];
  const float* Tf  = (const float*)d_in[1];
  const float* Tb  = (const float*)d_in[2];
  const float* Wg0 = (const float*)d_in[3];
  const float* bg0 = (const float*)d_in[4];
  const float* Wc0 = (const float*)d_in[5];
  const float* bc0 = (const float*)d_in[6];
  const float* g0  = (const float*)d_in[7];
  const float* be0 = (const float*)d_in[8];
  const float* Wg1 = (const float*)d_in[9];
  const float* bg1 = (const float*)d_in[10];
  const float* Wc1 = (const float*)d_in[11];
  const float* bc1 = (const float*)d_in[12];
  const float* g1  = (const float*)d_in[13];
  const float* be1 = (const float*)d_in[14];

  constexpr int B = 32, T = 8;
  constexpr long M = 16384;

  char* p = (char*)d_ws;
  auto carve = [&](size_t bytes) { char* r = p; p += (bytes + 255) & ~(size_t)255; return r; };
  u16* z0g  = (u16*)carve(M * 1024 * 2);
  u16* z0c  = (u16*)carve(M * 1024 * 2);
  u16* z1g  = (u16*)carve(M * 1792 * 2);
  u16* z1c  = (u16*)carve(M * 1792 * 2);
  u16* z0Tg = (u16*)carve(144L * M * 2);
  u16* z0Tc = (u16*)carve(128L * M * 2);
  u16* z1Tg = (u16*)carve(256L * M * 2);
  u16* z1Tc = (u16*)carve(128L * M * 2);
  float* ubuf = (float*)carve(M * 128 * 4);
  float* cbuf = (float*)carve(M * 128 * 4);
  u16* Tpow = (u16*)carve(6L * 512 * 512 * 2);   // Tf,Tf2,Tf3,Tb,Tb2,Tb3
  u16* TfT  = (u16*)carve(512L * 512 * 2);
  u16* TbT  = (u16*)carve(512L * 512 * 2);
  u16* Wg0t = (u16*)carve(256L * 1024 * 2);
  u16* Wc0t = (u16*)carve(128L * 1024 * 2);
  u16* Wg1t = (u16*)carve(256L * 1792 * 2);
  u16* Wc1t = (u16*)carve(128L * 1792 * 2);

  float* h0 = (float*)d_out;
  float* h1 = h0 + M * 128;

  hipMemsetAsync(d_out, 0, (size_t)out_size * 4, stream);
  zero_cols<<<1024, 256, 0, stream>>>(z0g, 1024, 16);
  zero_cols<<<1024, 256, 0, stream>>>(z1g, 1792, 128);
  hipMemsetAsync(z0Tg + 16L * M, 0, 128L * M * 2, stream);
  hipMemsetAsync(z1Tg + 128L * M, 0, 128L * M * 2, stream);

  cvtT<<<dim3(1024, 2), 256, 0, stream>>>(Tf, Tb, Tpow, TfT, TbT);
  gemm_pow<<<dim3(8, 8, 2), 256, 0, stream>>>(
      Tpow, TfT, Tpow + 1L * 262144, Tpow + 3L * 262144, TbT, Tpow + 4L * 262144);
  gemm_pow<<<dim3(8, 8, 2), 256, 0, stream>>>(
      Tpow + 1L * 262144, TfT, Tpow + 2L * 262144, Tpow + 4L * 262144, TbT, Tpow + 5L * 262144);
  wt_cvt<<<(256 * 1024 + 255) / 256, 256, 0, stream>>>(Wg0, Wg0t, 1008, 1024, 256);
  wt_cvt<<<(128 * 1024 + 255) / 256, 256, 0, stream>>>(Wc0, Wc0t, 1008, 1024, 128);
  wt_cvt<<<(256 * 1792 + 255) / 256, 256, 0, stream>>>(Wg1, Wg1t, 1792, 1792, 256);
  wt_cvt<<<(128 * 1792 + 255) / 256, 256, 0, stream>>>(Wc1, Wc1t, 1792, 1792, 128);

  for (int t = 0; t < T; t++) {
    // ======== layer 0 (C=144, Kpad=1024) ========
    xk<<<64, 256, 0, stream>>>(x_seq, t, z0g, z0c, z0Tg);
    // x-part diffusion (16 ch), dual-write into z0c
    gemm_diff<256, 16, 4, 1><<<dim3(2, 1, 6 * B), 256, 0, stream>>>(
        Tpow, z0Tg, z0g, 1024, 144, 0, z0c, 16);
    // h-part diffusion (128 ch)
    gemm_diff<128, 128, 2, 2><<<dim3(4, 1, 6 * B), 256, 0, stream>>>(
        Tpow, z0Tg + 16L * M, z0g, 1024, 144, 16, nullptr, 0);
    gemm_proj<64, 128, 1><<<dim3(256, 2), 256, 0, stream>>>(
        z0g, 1024, Wg0t, 1024, bg0, h0, z0c, 1024, 16, z0Tc, ubuf);
    gemm_diff<128, 128, 2, 2><<<dim3(4, 1, 6 * B), 256, 0, stream>>>(
        Tpow, z0Tc, z0c, 1024, 144, 16, nullptr, 0);
    gemm_proj<64, 64, 2><<<dim3(256, 2), 256, 0, stream>>>(
        z0c, 1024, Wc0t, 1024, bc0, nullptr, nullptr, 0, 0, nullptr, cbuf);
    gru_ln<<<dim3(8, B), 256, 0, stream>>>(ubuf, cbuf, h0, g0, be0,
        z0g, 1024, 16, z1g, 1792, 0, z1c, 1792, 0, z0Tg, 16, z1Tg, 0);
    // ======== layer 1 (C=256, Kpad=1792) ========
    gemm_diff<128, 128, 2, 2><<<dim3(4, 2, 6 * B), 256, 0, stream>>>(
        Tpow, z1Tg, z1g, 1792, 256, 0, z1c, 128);
    gemm_proj<64, 128, 1><<<dim3(256, 2), 256, 0, stream>>>(
        z1g, 1792, Wg1t, 1792, bg1, h1, z1c, 1792, 128, z1Tc, ubuf);
    gemm_diff<128, 128, 2, 2><<<dim3(4, 1, 6 * B), 256, 0, stream>>>(
        Tpow, z1Tc, z1c, 1792, 256, 128, nullptr, 0);
    gemm_proj<64, 64, 2><<<dim3(256, 2), 256, 0, stream>>>(
        z1c, 1792, Wc1t, 1792, bc1, nullptr, nullptr, 0, 0, nullptr, cbuf);
    gru_ln<<<dim3(8, B), 256, 0, stream>>>(ubuf, cbuf, h1, g1, be1,
        z1g, 1792, 128, nullptr, 0, 0, nullptr, 0, 0, z1Tg, 128, nullptr, 0);
  }
}

// Round 5
// 2072.274 us; speedup vs baseline: 1.4023x; 1.4023x over previous
//
#include <hip/hip_runtime.h>
#include <hip/hip_bf16.h>
#include <math.h>

typedef unsigned short u16;
typedef __attribute__((ext_vector_type(8))) short short8;
typedef __attribute__((ext_vector_type(4))) float f32x4;

__device__ __forceinline__ u16 f2bf(float f) {
  union { float f; unsigned u; } v; v.f = f;
  unsigned r = v.u + 0x7fffu + ((v.u >> 16) & 1u);
  return (u16)(r >> 16);
}

// async global->LDS, 16B/lane. LDS dest is wave-uniform base; HW adds lane*16.
__device__ __forceinline__ void glds16(const u16* g, u16* l) {
  __builtin_amdgcn_global_load_lds(
      (const __attribute__((address_space(1))) void*)g,
      (__attribute__((address_space(3))) void*)l, 16, 0, 0);
}

// ===========================================================================
// Diffusion: out[(b*512+node)*ldz + (1+tc)*C + coff0 + ch] =
//            sum_k Tpow[tc][node][k] * zT[ch][b*512+k]
// zT layout: [ch][16384]. grid.z = b*6 + tc. Dual-write ch<Fdual into zdual.
// BK=64; LDS rows 128B. Bank-conflict fix (T2, rule #21): LDS dest linear,
// global SOURCE pre-swizzled (kc ^ (row&7)), ds_read applies the same XOR.
// ===========================================================================
template<int BM, int BN, int WR, int WC>
__global__ __launch_bounds__(256) void gemm_diff(
    const u16* __restrict__ Tpow, const u16* __restrict__ zT,
    u16* __restrict__ zout, int ldz, int C, int coff0,
    u16* __restrict__ zdual, int Fdual)
{
  constexpr int BK = 64;
  constexpr int FM = BM / (WR * 16), FN = BN / (WC * 16);
  constexpr int SLOTS = (BM + BN) * 8;       // 16B slots per K-tile (mult of 64)
  __shared__ u16 sm[(BM + BN) * BK];
  const int tid = threadIdx.x, lane = tid & 63, wid = tid >> 6;
  const int wr = wid / WC, wc = wid % WC;
  const int l15 = lane & 15, l4 = lane >> 4;
  const int m0 = blockIdx.x * BM;
  const int y0 = blockIdx.y * BN;
  const int b = blockIdx.z / 6, tc = blockIdx.z % 6;
  const u16* A = Tpow + (long)tc * 512 * 512;
  const u16* Bz = zT + (long)y0 * 16384 + b * 512;

  f32x4 acc[FM][FN] = {};
  for (int k0 = 0; k0 < 512; k0 += BK) {
    for (int s = tid; s < SLOTS; s += 256) {
      int row = s >> 3, kc = s & 7;
      int kcg = kc ^ (row & 7);
      const u16* gp;
      if (row < BM) gp = A + (long)(m0 + row) * 512 + k0 + kcg * 8;
      else gp = Bz + (long)(row - BM) * 16384 + k0 + kcg * 8;
      glds16(gp, sm + (s - lane) * 8);
    }
    __syncthreads();
    #pragma unroll
    for (int kk = 0; kk < 2; kk++) {
      short8 af[FM], bf[FN];
      #pragma unroll
      for (int i = 0; i < FM; i++) {
        int ar = wr * FM * 16 + i * 16 + l15;
        af[i] = *(const short8*)&sm[ar * BK + (((kk * 4 + l4) ^ (ar & 7)) << 3)];
      }
      #pragma unroll
      for (int j = 0; j < FN; j++) {
        int br = wc * FN * 16 + j * 16 + l15;
        bf[j] = *(const short8*)&sm[BM * BK + br * BK + (((kk * 4 + l4) ^ (br & 7)) << 3)];
      }
      #pragma unroll
      for (int i = 0; i < FM; i++)
        #pragma unroll
        for (int j = 0; j < FN; j++)
          acc[i][j] = __builtin_amdgcn_mfma_f32_16x16x32_bf16(af[i], bf[j], acc[i][j], 0, 0, 0);
    }
    __syncthreads();
  }

  const int tC = (1 + tc) * C;
  #pragma unroll
  for (int i = 0; i < FM; i++) {
    #pragma unroll
    for (int j = 0; j < FN; j++) {
      int node = m0 + wr * FM * 16 + i * 16 + l4 * 4;
      int ch = y0 + wc * FN * 16 + j * 16 + l15;
      #pragma unroll
      for (int rr = 0; rr < 4; rr++) {
        u16 v = f2bf(acc[i][j][rr]);
        long r = (long)b * 512 + node + rr;
        zout[r * ldz + tC + coff0 + ch] = v;
        if (Fdual && ch < Fdual) zdual[r * ldz + tC + ch] = v;
      }
    }
  }
}

// ===========================================================================
// Projection (giant-M): out(16384, Nout) = act(z(16384, K) @ W(Nout, K)^T + bias)
// MODE 1 (gates): n<128 -> rh = sig*hst -> zc[r*ldzc+Foff+n] (bf16) + zTc[n*16384+r];
//                 n>=128 -> ubuf[r*128+n-128] (fp32).
// MODE 2 (cand):  tanh -> outbuf[r*128+n] (fp32).
// BK=64 + same swizzled staging as gemm_diff.
// ===========================================================================
template<int BM, int BN, int MODE>
__global__ __launch_bounds__(256) void gemm_proj(
    const u16* __restrict__ Az, int ldA,
    const u16* __restrict__ W, int K,
    const float* __restrict__ bias,
    const float* __restrict__ hst,
    u16* __restrict__ zc, int ldzc, int Foff,
    u16* __restrict__ zTc,
    float* __restrict__ outbuf)
{
  constexpr int BK = 64;
  constexpr int FM = BM / 32, FN = BN / 32;   // 2x2 waves
  constexpr int SLOTS = (BM + BN) * 8;
  __shared__ u16 sm[(BM + BN) * BK];
  const int tid = threadIdx.x, lane = tid & 63, wid = tid >> 6;
  const int wr = wid >> 1, wc = wid & 1;
  const int l15 = lane & 15, l4 = lane >> 4;
  const int m0 = blockIdx.x * BM;
  const int n0 = blockIdx.y * BN;

  f32x4 acc[FM][FN] = {};
  for (int k0 = 0; k0 < K; k0 += BK) {
    for (int s = tid; s < SLOTS; s += 256) {
      int row = s >> 3, kc = s & 7;
      int kcg = kc ^ (row & 7);
      const u16* gp;
      if (row < BM) gp = Az + (long)(m0 + row) * ldA + k0 + kcg * 8;
      else gp = W + (long)(n0 + row - BM) * K + k0 + kcg * 8;
      glds16(gp, sm + (s - lane) * 8);
    }
    __syncthreads();
    #pragma unroll
    for (int kk = 0; kk < 2; kk++) {
      short8 af[FM], bf[FN];
      #pragma unroll
      for (int i = 0; i < FM; i++) {
        int ar = wr * FM * 16 + i * 16 + l15;
        af[i] = *(const short8*)&sm[ar * BK + (((kk * 4 + l4) ^ (ar & 7)) << 3)];
      }
      #pragma unroll
      for (int j = 0; j < FN; j++) {
        int br = wc * FN * 16 + j * 16 + l15;
        bf[j] = *(const short8*)&sm[BM * BK + br * BK + (((kk * 4 + l4) ^ (br & 7)) << 3)];
      }
      #pragma unroll
      for (int i = 0; i < FM; i++)
        #pragma unroll
        for (int j = 0; j < FN; j++)
          acc[i][j] = __builtin_amdgcn_mfma_f32_16x16x32_bf16(af[i], bf[j], acc[i][j], 0, 0, 0);
    }
    __syncthreads();
  }

  #pragma unroll
  for (int i = 0; i < FM; i++) {
    #pragma unroll
    for (int j = 0; j < FN; j++) {
      int mb = m0 + wr * FM * 16 + i * 16 + l4 * 4;
      int n = n0 + wc * FN * 16 + j * 16 + l15;
      #pragma unroll
      for (int rr = 0; rr < 4; rr++) {
        float v = acc[i][j][rr] + bias[n];
        long r = mb + rr;
        if constexpr (MODE == 1) {
          float g = 1.f / (1.f + expf(-v));
          if (n < 128) {
            float rh = g * hst[r * 128 + n];
            u16 hv = f2bf(rh);
            zc[r * ldzc + Foff + n] = hv;
            zTc[(long)n * 16384 + r] = hv;
          } else {
            outbuf[r * 128 + (n - 128)] = g;
          }
        } else {
          outbuf[r * 128 + n] = tanhf(v);
        }
      }
    }
  }
}

// ===========================================================================
// Fused GRU update + LayerNorm (H=128) + fan-out writes.
// Block: 64 nodes x 128 ch; grid (8, B).
// ===========================================================================
__global__ __launch_bounds__(256) void gru_ln(
    const float* __restrict__ ub, const float* __restrict__ cd,
    float* __restrict__ h, const float* __restrict__ gamma, const float* __restrict__ beta,
    u16* __restrict__ rm0, int ld0, int co0,
    u16* __restrict__ rm1, int ld1, int co1,
    u16* __restrict__ rm2, int ld2, int co2,
    u16* __restrict__ cm0, int ro0,
    u16* __restrict__ cm1, int ro1)
{
  __shared__ float hs[64][132];
  const int tid = threadIdx.x;
  const long b = blockIdx.y;
  const int n0 = blockIdx.x * 64;
  const long rbase = (b * 512 + n0) * 128;

  #pragma unroll
  for (int i = 0; i < 32; i++) {
    int idx = tid + i * 256;
    float u = ub[rbase + idx];
    float cc = cd[rbase + idx];
    float hv = h[rbase + idx];
    hs[idx >> 7][idx & 127] = (1.f - u) * hv + u * cc;
  }
  __syncthreads();

  const int rw = tid >> 2, sub = tid & 3;
  float s = 0.f, s2v = 0.f;
  #pragma unroll
  for (int i = 0; i < 32; i++) {
    float v = hs[rw][sub + 4 * i];
    s += v; s2v += v * v;
  }
  s += __shfl_xor(s, 1); s2v += __shfl_xor(s2v, 1);
  s += __shfl_xor(s, 2); s2v += __shfl_xor(s2v, 2);
  float mu = s * (1.f / 128.f);
  float var = s2v * (1.f / 128.f) - mu * mu;
  float rs = rsqrtf(var + 1e-5f);
  #pragma unroll
  for (int i = 0; i < 32; i++) {
    int c = sub + 4 * i;
    float v = (hs[rw][c] - mu) * rs * gamma[c] + beta[c];
    h[rbase + rw * 128 + c] = v;
    hs[rw][c] = v;
  }
  __syncthreads();

  #pragma unroll
  for (int i = 0; i < 32; i++) {
    int idx = tid + i * 256;
    int node = idx >> 7, c = idx & 127;
    u16 v = f2bf(hs[node][c]);
    long r = b * 512 + n0 + node;
    rm0[r * ld0 + co0 + c] = v;
    if (rm1) rm1[r * ld1 + co1 + c] = v;
    if (rm2) rm2[r * ld2 + co2 + c] = v;
  }
  const int c2 = tid >> 1, half = tid & 1;
  u16 tmp[32];
  #pragma unroll
  for (int i = 0; i < 32; i++) tmp[i] = f2bf(hs[half * 32 + i][c2]);
  const short8* tv = (const short8*)tmp;
  {
    long off = (long)(ro0 + c2) * 16384 + b * 512 + n0 + half * 32;
    #pragma unroll
    for (int q = 0; q < 4; q++) *(short8*)&cm0[off + q * 8] = tv[q];
  }
  if (cm1) {
    long off = (long)(ro1 + c2) * 16384 + b * 512 + n0 + half * 32;
    #pragma unroll
    for (int q = 0; q < 4; q++) *(short8*)&cm1[off + q * 8] = tv[q];
  }
}

// ===========================================================================
// small helpers
// ===========================================================================
__global__ __launch_bounds__(256) void xk(
    const float* __restrict__ xs, int t,
    u16* __restrict__ z0g, u16* __restrict__ z0c, u16* __restrict__ z0Tg)
{
  int r = blockIdx.x * 256 + threadIdx.x;       // 0..16383 = b*512+n
  int b = r >> 9, n = r & 511;
  const float* src = xs + (((long)b * 8 + t) * 512 + n) * 16;
  u16 tmp[16];
  #pragma unroll
  for (int f = 0; f < 16; f++) tmp[f] = f2bf(src[f]);
  const short8* tv = (const short8*)tmp;
  *(short8*)&z0g[(long)r * 1024] = tv[0];
  *(short8*)&z0g[(long)r * 1024 + 8] = tv[1];
  *(short8*)&z0c[(long)r * 1024] = tv[0];
  *(short8*)&z0c[(long)r * 1024 + 8] = tv[1];
  #pragma unroll
  for (int f = 0; f < 16; f++) z0Tg[(long)f * 16384 + r] = tmp[f];
}

__global__ void zero_cols(u16* __restrict__ z, int ld, int c0) {  // zero 128 cols
  int idx = blockIdx.x * 256 + threadIdx.x;     // 16384*16
  int r = idx >> 4, s = idx & 15;
  short8 zz = {};
  *(short8*)&z[(long)r * ld + c0 + s * 8] = zz;
}

__global__ void cvtT(const float* __restrict__ Tf, const float* __restrict__ Tb,
                     u16* __restrict__ Tpow, u16* __restrict__ TfT, u16* __restrict__ TbT)
{
  int idx = blockIdx.x * 256 + threadIdx.x;     // 262144
  int i = idx >> 9, j = idx & 511;
  const float* s = blockIdx.y ? Tb : Tf;
  u16* d = Tpow + (blockIdx.y ? 3 : 0) * 262144;
  u16* dT = blockIdx.y ? TbT : TfT;
  u16 v = f2bf(s[idx]);
  d[idx] = v;
  dT[(long)j * 512 + i] = v;
}

__global__ __launch_bounds__(256) void gemm_pow(
    const u16* __restrict__ A0, const u16* __restrict__ B0, u16* __restrict__ C0,
    const u16* __restrict__ A1, const u16* __restrict__ B1, u16* __restrict__ C1)
{
  constexpr int BM = 64, BN = 64, BK = 32;
  __shared__ u16 sm[(BM + BN) * BK];
  const int tid = threadIdx.x, lane = tid & 63, wid = tid >> 6;
  const int wr = wid >> 1, wc = wid & 1;
  const int l15 = lane & 15, l4 = lane >> 4;
  const int m0 = blockIdx.x * BM, n0 = blockIdx.y * BN;
  const u16* A = blockIdx.z ? A1 : A0;
  const u16* Bt = blockIdx.z ? B1 : B0;
  u16* Cc = blockIdx.z ? C1 : C0;

  f32x4 acc[2][2] = {};
  for (int k0 = 0; k0 < 512; k0 += BK) {
    for (int s = tid; s < (BM + BN) * 4; s += 256) {
      const u16* gp;
      if (s < BM * 4) { int m = s >> 2, kc = s & 3; gp = A + (long)(m0 + m) * 512 + k0 + kc * 8; }
      else { int q = s - BM * 4; int n = q >> 2, kc = q & 3; gp = Bt + (long)(n0 + n) * 512 + k0 + kc * 8; }
      glds16(gp, sm + (s - lane) * 8);
    }
    __syncthreads();
    short8 af[2], bf[2];
    #pragma unroll
    for (int i = 0; i < 2; i++)
      af[i] = *(const short8*)&sm[(wr * 32 + i * 16 + l15) * BK + l4 * 8];
    #pragma unroll
    for (int j = 0; j < 2; j++)
      bf[j] = *(const short8*)&sm[BM * BK + (wc * 32 + j * 16 + l15) * BK + l4 * 8];
    #pragma unroll
    for (int i = 0; i < 2; i++)
      #pragma unroll
      for (int j = 0; j < 2; j++)
        acc[i][j] = __builtin_amdgcn_mfma_f32_16x16x32_bf16(af[i], bf[j], acc[i][j], 0, 0, 0);
    __syncthreads();
  }
  #pragma unroll
  for (int i = 0; i < 2; i++)
    #pragma unroll
    for (int j = 0; j < 2; j++) {
      int mb = m0 + wr * 32 + i * 16 + l4 * 4;
      int n = n0 + wc * 32 + j * 16 + l15;
      #pragma unroll
      for (int rr = 0; rr < 4; rr++)
        Cc[(long)(mb + rr) * 512 + n] = f2bf(acc[i][j][rr]);
    }
}

__global__ void wt_cvt(const float* __restrict__ W, u16* __restrict__ Wt,
                       int Ksrc, int Kpad, int Nout) {
  long idx = (long)blockIdx.x * 256 + threadIdx.x;
  if (idx >= (long)Nout * Kpad) return;
  int o = (int)(idx / Kpad), k = (int)(idx % Kpad);
  Wt[idx] = f2bf(k < Ksrc ? W[(long)k * Nout + o] : 0.f);
}

// ===========================================================================
extern "C" void kernel_launch(void* const* d_in, const int* in_sizes, int n_in,
                              void* d_out, int out_size, void* d_ws, size_t ws_size,
                              hipStream_t stream) {
  const float* x_seq = (const float*)d_in[0];
  const float* Tf  = (const float*)d_in[1];
  const float* Tb  = (const float*)d_in[2];
  const float* Wg0 = (const float*)d_in[3];
  const float* bg0 = (const float*)d_in[4];
  const float* Wc0 = (const float*)d_in[5];
  const float* bc0 = (const float*)d_in[6];
  const float* g0  = (const float*)d_in[7];
  const float* be0 = (const float*)d_in[8];
  const float* Wg1 = (const float*)d_in[9];
  const float* bg1 = (const float*)d_in[10];
  const float* Wc1 = (const float*)d_in[11];
  const float* bc1 = (const float*)d_in[12];
  const float* g1  = (const float*)d_in[13];
  const float* be1 = (const float*)d_in[14];

  constexpr int B = 32, T = 8;
  constexpr long M = 16384;

  char* p = (char*)d_ws;
  auto carve = [&](size_t bytes) { char* r = p; p += (bytes + 255) & ~(size_t)255; return r; };
  u16* z0g  = (u16*)carve(M * 1024 * 2);
  u16* z0c  = (u16*)carve(M * 1024 * 2);
  u16* z1g  = (u16*)carve(M * 1792 * 2);
  u16* z1c  = (u16*)carve(M * 1792 * 2);
  u16* z0Tg = (u16*)carve(144L * M * 2);
  u16* z0Tc = (u16*)carve(128L * M * 2);
  u16* z1Tg = (u16*)carve(256L * M * 2);
  u16* z1Tc = (u16*)carve(128L * M * 2);
  float* ubuf = (float*)carve(M * 128 * 4);
  float* cbuf = (float*)carve(M * 128 * 4);
  u16* Tpow = (u16*)carve(6L * 512 * 512 * 2);   // Tf,Tf2,Tf3,Tb,Tb2,Tb3
  u16* TfT  = (u16*)carve(512L * 512 * 2);
  u16* TbT  = (u16*)carve(512L * 512 * 2);
  u16* Wg0t = (u16*)carve(256L * 1024 * 2);
  u16* Wc0t = (u16*)carve(128L * 1024 * 2);
  u16* Wg1t = (u16*)carve(256L * 1792 * 2);
  u16* Wc1t = (u16*)carve(128L * 1792 * 2);

  float* h0 = (float*)d_out;
  float* h1 = h0 + M * 128;

  hipMemsetAsync(d_out, 0, (size_t)out_size * 4, stream);
  zero_cols<<<1024, 256, 0, stream>>>(z0g, 1024, 16);
  zero_cols<<<1024, 256, 0, stream>>>(z1g, 1792, 128);
  hipMemsetAsync(z0Tg + 16L * M, 0, 128L * M * 2, stream);
  hipMemsetAsync(z1Tg + 128L * M, 0, 128L * M * 2, stream);

  cvtT<<<dim3(1024, 2), 256, 0, stream>>>(Tf, Tb, Tpow, TfT, TbT);
  gemm_pow<<<dim3(8, 8, 2), 256, 0, stream>>>(
      Tpow, TfT, Tpow + 1L * 262144, Tpow + 3L * 262144, TbT, Tpow + 4L * 262144);
  gemm_pow<<<dim3(8, 8, 2), 256, 0, stream>>>(
      Tpow + 1L * 262144, TfT, Tpow + 2L * 262144, Tpow + 4L * 262144, TbT, Tpow + 5L * 262144);
  wt_cvt<<<(256 * 1024 + 255) / 256, 256, 0, stream>>>(Wg0, Wg0t, 1008, 1024, 256);
  wt_cvt<<<(128 * 1024 + 255) / 256, 256, 0, stream>>>(Wc0, Wc0t, 1008, 1024, 128);
  wt_cvt<<<(256 * 1792 + 255) / 256, 256, 0, stream>>>(Wg1, Wg1t, 1792, 1792, 256);
  wt_cvt<<<(128 * 1792 + 255) / 256, 256, 0, stream>>>(Wc1, Wc1t, 1792, 1792, 128);

  for (int t = 0; t < T; t++) {
    // ======== layer 0 (C=144, Kpad=1024) ========
    xk<<<64, 256, 0, stream>>>(x_seq, t, z0g, z0c, z0Tg);
    // gates diffusion, all 144 ch, dual-write x-part (ch<16) into z0c
    gemm_diff<128, 48, 4, 1><<<dim3(4, 3, 6 * B), 256, 0, stream>>>(
        Tpow, z0Tg, z0g, 1024, 144, 0, z0c, 16);
    gemm_proj<64, 64, 1><<<dim3(256, 4), 256, 0, stream>>>(
        z0g, 1024, Wg0t, 1024, bg0, h0, z0c, 1024, 16, z0Tc, ubuf);
    // cand diffusion: r*h half only (x-half reused via dual-write)
    gemm_diff<128, 64, 2, 2><<<dim3(4, 2, 6 * B), 256, 0, stream>>>(
        Tpow, z0Tc, z0c, 1024, 144, 16, nullptr, 0);
    gemm_proj<64, 64, 2><<<dim3(256, 2), 256, 0, stream>>>(
        z0c, 1024, Wc0t, 1024, bc0, nullptr, nullptr, 0, 0, nullptr, cbuf);
    gru_ln<<<dim3(8, B), 256, 0, stream>>>(ubuf, cbuf, h0, g0, be0,
        z0g, 1024, 16, z1g, 1792, 0, z1c, 1792, 0, z0Tg, 16, z1Tg, 0);
    // ======== layer 1 (C=256, Kpad=1792) ========
    gemm_diff<128, 64, 2, 2><<<dim3(4, 4, 6 * B), 256, 0, stream>>>(
        Tpow, z1Tg, z1g, 1792, 256, 0, z1c, 128);
    gemm_proj<64, 64, 1><<<dim3(256, 4), 256, 0, stream>>>(
        z1g, 1792, Wg1t, 1792, bg1, h1, z1c, 1792, 128, z1Tc, ubuf);
    gemm_diff<128, 64, 2, 2><<<dim3(4, 2, 6 * B), 256, 0, stream>>>(
        Tpow, z1Tc, z1c, 1792, 256, 128, nullptr, 0);
    gemm_proj<64, 64, 2><<<dim3(256, 2), 256, 0, stream>>>(
        z1c, 1792, Wc1t, 1792, bc1, nullptr, nullptr, 0, 0, nullptr, cbuf);
    gru_ln<<<dim3(8, B), 256, 0, stream>>>(ubuf, cbuf, h1, g1, be1,
        z1g, 1792, 128, nullptr, 0, 0, nullptr, 0, 0, z1Tg, 128, nullptr, 0);
  }
}

// Round 6
// 1692.850 us; speedup vs baseline: 1.7166x; 1.2241x over previous
//
#include <hip/hip_runtime.h>
#include <hip/hip_bf16.h>
#include <math.h>

typedef unsigned short u16;
typedef __attribute__((ext_vector_type(8))) short short8;
typedef __attribute__((ext_vector_type(4))) float f32x4;

__device__ __forceinline__ u16 f2bf(float f) {
  union { float f; unsigned u; } v; v.f = f;
  unsigned r = v.u + 0x7fffu + ((v.u >> 16) & 1u);
  return (u16)(r >> 16);
}

// async global->LDS, 16B/lane. LDS dest is wave-uniform base; HW adds lane*16.
__device__ __forceinline__ void glds16(const u16* g, u16* l) {
  __builtin_amdgcn_global_load_lds(
      (const __attribute__((address_space(1))) void*)g,
      (__attribute__((address_space(3))) void*)l, 16, 0, 0);
}

// ===========================================================================
// Diffusion: out[(b*512+node)*ldz + (1+tc)*C + coff0 + ch] =
//            sum_k Tpow[tc][node][k] * zT[ch][b*512+k]
// zT layout: [ch][16384]. grid.z = b*6 + tc. Dual-write ch<Fdual into zdual.
// BK=64, swizzled staging (source-XOR kc^(row&7), linear LDS dest, XOR read).
// 2-phase prefetch: stage(t+1) issued before compute(t); 1 barrier/tile.
// Staging pointers are loop-hoisted induction variables (+BK per tile).
// ===========================================================================
template<int BM, int BN, int WR, int WC>
__global__ __launch_bounds__(256) void gemm_diff(
    const u16* __restrict__ Tpow, const u16* __restrict__ zT,
    u16* __restrict__ zout, int ldz, int C, int coff0,
    u16* __restrict__ zdual, int Fdual)
{
  constexpr int BK = 64;
  constexpr int FM = BM / (WR * 16), FN = BN / (WC * 16);
  constexpr int SLOTS = (BM + BN) * 8;       // 16B slots per K-tile
  constexpr int NS = (SLOTS + 255) / 256;
  constexpr int HALF = (BM + BN) * BK;       // u16 per LDS buffer
  __shared__ u16 sm[2 * HALF];
  const int tid = threadIdx.x, lane = tid & 63, wid = tid >> 6;
  const int wr = wid / WC, wc = wid % WC;
  const int l15 = lane & 15, l4 = lane >> 4;
  const int m0 = blockIdx.x * BM;
  const int y0 = blockIdx.y * BN;
  const int b = blockIdx.z / 6, tc = blockIdx.z % 6;
  const u16* A = Tpow + (long)tc * 262144;
  const u16* Bz = zT + (long)y0 * 16384 + b * 512;
  const int lb = (tid - lane) * 8;           // wave-uniform LDS dest (u16 units)

  const u16* gp[NS];
  #pragma unroll
  for (int i = 0; i < NS; i++) {
    int s = tid + i * 256;
    int row = s >> 3, kc = s & 7;
    int kcg = kc ^ (row & 7);
    gp[i] = (row < BM) ? A + (long)(m0 + row) * 512 + kcg * 8
                       : Bz + (long)(row - BM) * 16384 + kcg * 8;
  }

  auto stage = [&](int buf) {
    u16* base = sm + buf * HALF + lb;
    #pragma unroll
    for (int i = 0; i < NS; i++) {
      if (i * 256 + 256 <= SLOTS || tid < SLOTS - i * 256)
        glds16(gp[i], base + i * 2048);
    }
    #pragma unroll
    for (int i = 0; i < NS; i++) gp[i] += BK;
  };

  f32x4 acc[FM][FN] = {};
  auto compute = [&](int buf) {
    const u16* smc = sm + buf * HALF;
    #pragma unroll
    for (int kk = 0; kk < 2; kk++) {
      short8 af[FM], bf[FN];
      #pragma unroll
      for (int i = 0; i < FM; i++) {
        int ar = wr * FM * 16 + i * 16 + l15;
        af[i] = *(const short8*)&smc[ar * BK + (((kk * 4 + l4) ^ (ar & 7)) << 3)];
      }
      #pragma unroll
      for (int j = 0; j < FN; j++) {
        int br = wc * FN * 16 + j * 16 + l15;
        bf[j] = *(const short8*)&smc[BM * BK + br * BK + (((kk * 4 + l4) ^ (br & 7)) << 3)];
      }
      #pragma unroll
      for (int i = 0; i < FM; i++)
        #pragma unroll
        for (int j = 0; j < FN; j++)
          acc[i][j] = __builtin_amdgcn_mfma_f32_16x16x32_bf16(af[i], bf[j], acc[i][j], 0, 0, 0);
    }
  };

  stage(0);
  __syncthreads();
  int cur = 0;
  for (int t = 0; t < 7; t++) {              // NT = 512/64 = 8
    stage(cur ^ 1);
    compute(cur);
    __syncthreads();
    cur ^= 1;
  }
  compute(cur);

  const int tC = (1 + tc) * C;
  #pragma unroll
  for (int i = 0; i < FM; i++) {
    #pragma unroll
    for (int j = 0; j < FN; j++) {
      int node = m0 + wr * FM * 16 + i * 16 + l4 * 4;
      int ch = y0 + wc * FN * 16 + j * 16 + l15;
      #pragma unroll
      for (int rr = 0; rr < 4; rr++) {
        u16 v = f2bf(acc[i][j][rr]);
        long r = (long)b * 512 + node + rr;
        zout[r * ldz + tC + coff0 + ch] = v;
        if (Fdual && ch < Fdual) zdual[r * ldz + tC + ch] = v;
      }
    }
  }
}

// ===========================================================================
// Projection (giant-M): out(16384, Nout) = act(z(16384, K) @ W(Nout, K)^T + b)
// A rows read from Ag/Ac selected per K-chunk by ((k0>>7)&1) — lets L1 cand
// reuse z1g's h0-diffused halves (pass Ag==Ac when no split).
// MODE 1 (gates): n<128 -> rh=sig*hst -> zc[r*ldzc+Foff+n] + zTc[n*16384+r];
//                 n>=128 -> ubuf fp32.  MODE 2 (cand): tanh -> outbuf fp32.
// ===========================================================================
template<int BM, int BN, int MODE>
__global__ __launch_bounds__(256) void gemm_proj(
    const u16* __restrict__ Ag, const u16* __restrict__ Ac, int ldA,
    const u16* __restrict__ W, int K,
    const float* __restrict__ bias,
    const float* __restrict__ hst,
    u16* __restrict__ zc, int ldzc, int Foff,
    u16* __restrict__ zTc,
    float* __restrict__ outbuf)
{
  constexpr int BK = 64;
  constexpr int FM = BM / 32, FN = BN / 32;   // 2x2 waves
  constexpr int NSA = BM / 32, NSB = BN / 32; // 32 rows per slot-group
  constexpr int HALF = (BM + BN) * BK;
  __shared__ u16 sm[2 * HALF];
  const int tid = threadIdx.x, lane = tid & 63, wid = tid >> 6;
  const int wr = wid >> 1, wc = wid & 1;
  const int l15 = lane & 15, l4 = lane >> 4;
  const int m0 = blockIdx.x * BM;
  const int n0 = blockIdx.y * BN;
  const int lb = (tid - lane) * 8;

  unsigned aoff[NSA];
  const u16* wp[NSB];
  #pragma unroll
  for (int i = 0; i < NSA; i++) {
    int s = tid + i * 256;
    int row = s >> 3, kc = s & 7;
    int kcg = kc ^ (row & 7);
    aoff[i] = (unsigned)((m0 + row) * ldA + kcg * 8);
  }
  #pragma unroll
  for (int i = 0; i < NSB; i++) {
    int s = tid + (NSA + i) * 256;
    int row = s >> 3, kc = s & 7;
    int kcg = kc ^ (row & 7);
    wp[i] = W + (long)(n0 + row - BM) * K + kcg * 8;
  }

  auto stage = [&](int buf, int koff) {
    u16* base = sm + buf * HALF + lb;
    const u16* ab = ((koff >> 7) & 1) ? Ac : Ag;
    #pragma unroll
    for (int i = 0; i < NSA; i++) glds16(ab + aoff[i] + koff, base + i * 2048);
    #pragma unroll
    for (int i = 0; i < NSB; i++) glds16(wp[i], base + (NSA + i) * 2048);
    #pragma unroll
    for (int i = 0; i < NSB; i++) wp[i] += BK;
  };

  f32x4 acc[FM][FN] = {};
  auto compute = [&](int buf) {
    const u16* smc = sm + buf * HALF;
    #pragma unroll
    for (int kk = 0; kk < 2; kk++) {
      short8 af[FM], bf[FN];
      #pragma unroll
      for (int i = 0; i < FM; i++) {
        int ar = wr * FM * 16 + i * 16 + l15;
        af[i] = *(const short8*)&smc[ar * BK + (((kk * 4 + l4) ^ (ar & 7)) << 3)];
      }
      #pragma unroll
      for (int j = 0; j < FN; j++) {
        int br = wc * FN * 16 + j * 16 + l15;
        bf[j] = *(const short8*)&smc[BM * BK + br * BK + (((kk * 4 + l4) ^ (br & 7)) << 3)];
      }
      #pragma unroll
      for (int i = 0; i < FM; i++)
        #pragma unroll
        for (int j = 0; j < FN; j++)
          acc[i][j] = __builtin_amdgcn_mfma_f32_16x16x32_bf16(af[i], bf[j], acc[i][j], 0, 0, 0);
    }
  };

  stage(0, 0);
  __syncthreads();
  int cur = 0;
  const int NT = K >> 6;
  for (int t = 1; t < NT; t++) {
    stage(cur ^ 1, t * 64);
    compute(cur);
    __syncthreads();
    cur ^= 1;
  }
  compute(cur);

  #pragma unroll
  for (int i = 0; i < FM; i++) {
    #pragma unroll
    for (int j = 0; j < FN; j++) {
      int mb = m0 + wr * FM * 16 + i * 16 + l4 * 4;
      int n = n0 + wc * FN * 16 + j * 16 + l15;
      #pragma unroll
      for (int rr = 0; rr < 4; rr++) {
        float v = acc[i][j][rr] + bias[n];
        long r = mb + rr;
        if constexpr (MODE == 1) {
          float g = 1.f / (1.f + expf(-v));
          if (n < 128) {
            float rh = g * hst[r * 128 + n];
            u16 hv = f2bf(rh);
            zc[r * ldzc + Foff + n] = hv;
            zTc[(long)n * 16384 + r] = hv;
          } else {
            outbuf[r * 128 + (n - 128)] = g;
          }
        } else {
          outbuf[r * 128 + n] = tanhf(v);
        }
      }
    }
  }
}

// ===========================================================================
// Fused GRU update + LayerNorm (H=128) + fan-out writes.
// Block: 64 nodes x 128 ch; grid (8, B).
// ===========================================================================
__global__ __launch_bounds__(256) void gru_ln(
    const float* __restrict__ ub, const float* __restrict__ cd,
    float* __restrict__ h, const float* __restrict__ gamma, const float* __restrict__ beta,
    u16* __restrict__ rm0, int ld0, int co0,
    u16* __restrict__ rm1, int ld1, int co1,
    u16* __restrict__ cm0, int ro0,
    u16* __restrict__ cm1, int ro1)
{
  __shared__ float hs[64][132];
  const int tid = threadIdx.x;
  const long b = blockIdx.y;
  const int n0 = blockIdx.x * 64;
  const long rbase = (b * 512 + n0) * 128;

  #pragma unroll
  for (int i = 0; i < 32; i++) {
    int idx = tid + i * 256;
    float u = ub[rbase + idx];
    float cc = cd[rbase + idx];
    float hv = h[rbase + idx];
    hs[idx >> 7][idx & 127] = (1.f - u) * hv + u * cc;
  }
  __syncthreads();

  const int rw = tid >> 2, sub = tid & 3;
  float s = 0.f, s2v = 0.f;
  #pragma unroll
  for (int i = 0; i < 32; i++) {
    float v = hs[rw][sub + 4 * i];
    s += v; s2v += v * v;
  }
  s += __shfl_xor(s, 1); s2v += __shfl_xor(s2v, 1);
  s += __shfl_xor(s, 2); s2v += __shfl_xor(s2v, 2);
  float mu = s * (1.f / 128.f);
  float var = s2v * (1.f / 128.f) - mu * mu;
  float rs = rsqrtf(var + 1e-5f);
  #pragma unroll
  for (int i = 0; i < 32; i++) {
    int c = sub + 4 * i;
    float v = (hs[rw][c] - mu) * rs * gamma[c] + beta[c];
    h[rbase + rw * 128 + c] = v;
    hs[rw][c] = v;
  }
  __syncthreads();

  #pragma unroll
  for (int i = 0; i < 32; i++) {
    int idx = tid + i * 256;
    int node = idx >> 7, c = idx & 127;
    u16 v = f2bf(hs[node][c]);
    long r = b * 512 + n0 + node;
    rm0[r * ld0 + co0 + c] = v;
    if (rm1) rm1[r * ld1 + co1 + c] = v;
  }
  const int c2 = tid >> 1, half = tid & 1;
  u16 tmp[32];
  #pragma unroll
  for (int i = 0; i < 32; i++) tmp[i] = f2bf(hs[half * 32 + i][c2]);
  const short8* tv = (const short8*)tmp;
  {
    long off = (long)(ro0 + c2) * 16384 + b * 512 + n0 + half * 32;
    #pragma unroll
    for (int q = 0; q < 4; q++) *(short8*)&cm0[off + q * 8] = tv[q];
  }
  if (cm1) {
    long off = (long)(ro1 + c2) * 16384 + b * 512 + n0 + half * 32;
    #pragma unroll
    for (int q = 0; q < 4; q++) *(short8*)&cm1[off + q * 8] = tv[q];
  }
}

// ===========================================================================
// small helpers
// ===========================================================================
__global__ __launch_bounds__(256) void xk(
    const float* __restrict__ xs, int t,
    u16* __restrict__ z0g, u16* __restrict__ z0c, u16* __restrict__ z0Tg)
{
  int r = blockIdx.x * 256 + threadIdx.x;       // 0..16383 = b*512+n
  int b = r >> 9, n = r & 511;
  const float* src = xs + (((long)b * 8 + t) * 512 + n) * 16;
  u16 tmp[16];
  #pragma unroll
  for (int f = 0; f < 16; f++) tmp[f] = f2bf(src[f]);
  const short8* tv = (const short8*)tmp;
  *(short8*)&z0g[(long)r * 1024] = tv[0];
  *(short8*)&z0g[(long)r * 1024 + 8] = tv[1];
  *(short8*)&z0c[(long)r * 1024] = tv[0];
  *(short8*)&z0c[(long)r * 1024 + 8] = tv[1];
  #pragma unroll
  for (int f = 0; f < 16; f++) z0Tg[(long)f * 16384 + r] = tmp[f];
}

__global__ void zero_cols(u16* __restrict__ z, int ld, int c0) {  // zero 128 cols
  int idx = blockIdx.x * 256 + threadIdx.x;     // 16384*16
  int r = idx >> 4, s = idx & 15;
  short8 zz = {};
  *(short8*)&z[(long)r * ld + c0 + s * 8] = zz;
}

__global__ void cvtT(const float* __restrict__ Tf, const float* __restrict__ Tb,
                     u16* __restrict__ Tpow, u16* __restrict__ TfT, u16* __restrict__ TbT)
{
  int idx = blockIdx.x * 256 + threadIdx.x;     // 262144
  int i = idx >> 9, j = idx & 511;
  const float* s = blockIdx.y ? Tb : Tf;
  u16* d = Tpow + (blockIdx.y ? 3 : 0) * 262144;
  u16* dT = blockIdx.y ? TbT : TfT;
  u16 v = f2bf(s[idx]);
  d[idx] = v;
  dT[(long)j * 512 + i] = v;
}

__global__ __launch_bounds__(256) void gemm_pow(
    const u16* __restrict__ A0, const u16* __restrict__ B0, u16* __restrict__ C0,
    const u16* __restrict__ A1, const u16* __restrict__ B1, u16* __restrict__ C1)
{
  constexpr int BM = 64, BN = 64, BK = 32;
  __shared__ u16 sm[(BM + BN) * BK];
  const int tid = threadIdx.x, lane = tid & 63, wid = tid >> 6;
  const int wr = wid >> 1, wc = wid & 1;
  const int l15 = lane & 15, l4 = lane >> 4;
  const int m0 = blockIdx.x * BM, n0 = blockIdx.y * BN;
  const u16* A = blockIdx.z ? A1 : A0;
  const u16* Bt = blockIdx.z ? B1 : B0;
  u16* Cc = blockIdx.z ? C1 : C0;

  f32x4 acc[2][2] = {};
  for (int k0 = 0; k0 < 512; k0 += BK) {
    for (int s = tid; s < (BM + BN) * 4; s += 256) {
      const u16* gp;
      if (s < BM * 4) { int m = s >> 2, kc = s & 3; gp = A + (long)(m0 + m) * 512 + k0 + kc * 8; }
      else { int q = s - BM * 4; int n = q >> 2, kc = q & 3; gp = Bt + (long)(n0 + n) * 512 + k0 + kc * 8; }
      glds16(gp, sm + (s - lane) * 8);
    }
    __syncthreads();
    short8 af[2], bf[2];
    #pragma unroll
    for (int i = 0; i < 2; i++)
      af[i] = *(const short8*)&sm[(wr * 32 + i * 16 + l15) * BK + l4 * 8];
    #pragma unroll
    for (int j = 0; j < 2; j++)
      bf[j] = *(const short8*)&sm[BM * BK + (wc * 32 + j * 16 + l15) * BK + l4 * 8];
    #pragma unroll
    for (int i = 0; i < 2; i++)
      #pragma unroll
      for (int j = 0; j < 2; j++)
        acc[i][j] = __builtin_amdgcn_mfma_f32_16x16x32_bf16(af[i], bf[j], acc[i][j], 0, 0, 0);
    __syncthreads();
  }
  #pragma unroll
  for (int i = 0; i < 2; i++)
    #pragma unroll
    for (int j = 0; j < 2; j++) {
      int mb = m0 + wr * 32 + i * 16 + l4 * 4;
      int n = n0 + wc * 32 + j * 16 + l15;
      #pragma unroll
      for (int rr = 0; rr < 4; rr++)
        Cc[(long)(mb + rr) * 512 + n] = f2bf(acc[i][j][rr]);
    }
}

__global__ void wt_cvt(const float* __restrict__ W, u16* __restrict__ Wt,
                       int Ksrc, int Kpad, int Nout) {
  long idx = (long)blockIdx.x * 256 + threadIdx.x;
  if (idx >= (long)Nout * Kpad) return;
  int o = (int)(idx / Kpad), k = (int)(idx % Kpad);
  Wt[idx] = f2bf(k < Ksrc ? W[(long)k * Nout + o] : 0.f);
}

// ===========================================================================
extern "C" void kernel_launch(void* const* d_in, const int* in_sizes, int n_in,
                              void* d_out, int out_size, void* d_ws, size_t ws_size,
                              hipStream_t stream) {
  const float* x_seq = (const float*)d_in[0];
  const float* Tf  = (const float*)d_in[1];
  const float* Tb  = (const float*)d_in[2];
  const float* Wg0 = (const float*)d_in[3];
  const float* bg0 = (const float*)d_in[4];
  const float* Wc0 = (const float*)d_in[5];
  const float* bc0 = (const float*)d_in[6];
  const float* g0  = (const float*)d_in[7];
  const float* be0 = (const float*)d_in[8];
  const float* Wg1 = (const float*)d_in[9];
  const float* bg1 = (const float*)d_in[10];
  const float* Wc1 = (const float*)d_in[11];
  const float* bc1 = (const float*)d_in[12];
  const float* g1  = (const float*)d_in[13];
  const float* be1 = (const float*)d_in[14];

  constexpr int B = 32, T = 8;
  constexpr long M = 16384;

  char* p = (char*)d_ws;
  auto carve = [&](size_t bytes) { char* r = p; p += (bytes + 255) & ~(size_t)255; return r; };
  u16* z0g  = (u16*)carve(M * 1024 * 2);
  u16* z0c  = (u16*)carve(M * 1024 * 2);
  u16* z1g  = (u16*)carve(M * 1792 * 2);
  u16* z1c  = (u16*)carve(M * 1792 * 2);
  u16* z0Tg = (u16*)carve(144L * M * 2);
  u16* z0Tc = (u16*)carve(128L * M * 2);
  u16* z1Tg = (u16*)carve(256L * M * 2);
  u16* z1Tc = (u16*)carve(128L * M * 2);
  float* ubuf = (float*)carve(M * 128 * 4);
  float* cbuf = (float*)carve(M * 128 * 4);
  u16* Tpow = (u16*)carve(6L * 512 * 512 * 2);   // Tf,Tf2,Tf3,Tb,Tb2,Tb3
  u16* TfT  = (u16*)carve(512L * 512 * 2);
  u16* TbT  = (u16*)carve(512L * 512 * 2);
  u16* Wg0t = (u16*)carve(256L * 1024 * 2);
  u16* Wc0t = (u16*)carve(128L * 1024 * 2);
  u16* Wg1t = (u16*)carve(256L * 1792 * 2);
  u16* Wc1t = (u16*)carve(128L * 1792 * 2);

  float* h0 = (float*)d_out;
  float* h1 = h0 + M * 128;

  hipMemsetAsync(d_out, 0, (size_t)out_size * 4, stream);
  zero_cols<<<1024, 256, 0, stream>>>(z0g, 1024, 16);
  zero_cols<<<1024, 256, 0, stream>>>(z1g, 1792, 128);
  hipMemsetAsync(z0Tg + 16L * M, 0, 128L * M * 2, stream);
  hipMemsetAsync(z1Tg + 128L * M, 0, 128L * M * 2, stream);

  cvtT<<<dim3(1024, 2), 256, 0, stream>>>(Tf, Tb, Tpow, TfT, TbT);
  gemm_pow<<<dim3(8, 8, 2), 256, 0, stream>>>(
      Tpow, TfT, Tpow + 1L * 262144, Tpow + 3L * 262144, TbT, Tpow + 4L * 262144);
  gemm_pow<<<dim3(8, 8, 2), 256, 0, stream>>>(
      Tpow + 1L * 262144, TfT, Tpow + 2L * 262144, Tpow + 4L * 262144, TbT, Tpow + 5L * 262144);
  wt_cvt<<<(256 * 1024 + 255) / 256, 256, 0, stream>>>(Wg0, Wg0t, 1008, 1024, 256);
  wt_cvt<<<(128 * 1024 + 255) / 256, 256, 0, stream>>>(Wc0, Wc0t, 1008, 1024, 128);
  wt_cvt<<<(256 * 1792 + 255) / 256, 256, 0, stream>>>(Wg1, Wg1t, 1792, 1792, 256);
  wt_cvt<<<(128 * 1792 + 255) / 256, 256, 0, stream>>>(Wc1, Wc1t, 1792, 1792, 128);

  for (int t = 0; t < T; t++) {
    // ======== layer 0 (C=144, Kpad=1024) ========
    xk<<<64, 256, 0, stream>>>(x_seq, t, z0g, z0c, z0Tg);
    // gates diffusion, all 144 ch, dual-write x-part (ch<16) into z0c
    gemm_diff<128, 48, 4, 1><<<dim3(4, 3, 6 * B), 256, 0, stream>>>(
        Tpow, z0Tg, z0g, 1024, 144, 0, z0c, 16);
    gemm_proj<64, 64, 1><<<dim3(256, 4), 256, 0, stream>>>(
        z0g, z0g, 1024, Wg0t, 1024, bg0, h0, z0c, 1024, 16, z0Tc, ubuf);
    // cand diffusion: r*h half only (x-half reused via dual-write)
    gemm_diff<128, 64, 2, 2><<<dim3(4, 2, 6 * B), 256, 0, stream>>>(
        Tpow, z0Tc, z0c, 1024, 144, 16, nullptr, 0);
    gemm_proj<64, 64, 2><<<dim3(256, 2), 256, 0, stream>>>(
        z0c, z0c, 1024, Wc0t, 1024, bc0, nullptr, nullptr, 0, 0, nullptr, cbuf);
    gru_ln<<<dim3(8, B), 256, 0, stream>>>(ubuf, cbuf, h0, g0, be0,
        z0g, 1024, 16, z1g, 1792, 0, z0Tg, 16, z1Tg, 0);
    // ======== layer 1 (C=256, Kpad=1792) ========
    gemm_diff<128, 64, 2, 2><<<dim3(4, 4, 6 * B), 256, 0, stream>>>(
        Tpow, z1Tg, z1g, 1792, 256, 0, nullptr, 0);
    gemm_proj<64, 64, 1><<<dim3(256, 4), 256, 0, stream>>>(
        z1g, z1g, 1792, Wg1t, 1792, bg1, h1, z1c, 1792, 128, z1Tc, ubuf);
    gemm_diff<128, 64, 2, 2><<<dim3(4, 2, 6 * B), 256, 0, stream>>>(
        Tpow, z1Tc, z1c, 1792, 256, 128, nullptr, 0);
    // cand proj: h0-diffused halves read from z1g, r*h1 halves from z1c
    gemm_proj<64, 64, 2><<<dim3(256, 2), 256, 0, stream>>>(
        z1g, z1c, 1792, Wc1t, 1792, bc1, nullptr, nullptr, 0, 0, nullptr, cbuf);
    gru_ln<<<dim3(8, B), 256, 0, stream>>>(ubuf, cbuf, h1, g1, be1,
        z1g, 1792, 128, nullptr, 0, 0, z1Tg, 128, nullptr, 0);
  }
}